// Round 2
// baseline (258.609 us; speedup 1.0000x reference)
//
#include <hip/hip_runtime.h>
#include <math.h>

// Problem constants (from reference)
#define BB 32
#define TT 4096
#define NN 11
#define FF 16
#define HH 32
#define LN_EPS 1e-5f

// total (token, m) work items = B*T*N = 1,441,792 = 5632 * 256
#define TOTAL_ITEMS (BB * TT * NN)

// tanh-form GELU as sigmoid: gelu(v) = v * sigmoid(1.5957691216 * (v + 0.044715 v^3))
// max abs deviation from exact-erf GELU ~3e-3, well under the 7.09e-2 threshold.
__device__ __forceinline__ float fast_gelu(float v) {
    const float v2 = v * v;
    const float c  = fmaf(0.044715f, v2, 1.0f);   // 1 + 0.044715 v^2
    const float t  = v * c * 1.5957691216057308f; // 2 * sqrt(2/pi) * (v + 0.044715 v^3)
    const float e  = __expf(-t);                  // v_exp_f32 (+1 mul by log2e)
    const float r  = __builtin_amdgcn_rcpf(1.0f + e);
    return v * r;
}

__global__ __launch_bounds__(256) void fused_proj_mlp_kernel(
    const float* __restrict__ x,        // [B,T,N,F]
    const int*   __restrict__ lab_idx,  // [B]
    const float* __restrict__ proj,     // [L,N,N]  (n,m)
    const float* __restrict__ bias,     // [L,1,N,F]
    const float* __restrict__ w1,       // [F,H]
    const float* __restrict__ b1,       // [H]
    const float* __restrict__ ln_g,     // [H]
    const float* __restrict__ ln_b,     // [H]
    const float* __restrict__ w2,       // [H,F]
    const float* __restrict__ b2,       // [F]
    float*       __restrict__ out)      // [B,T,N,F]
{
    const unsigned w = blockIdx.x * 256u + threadIdx.x;
    if (w >= TOTAL_ITEMS) return;

    const unsigned token = w / 11u;          // magic-mul division
    const unsigned m     = w - token * 11u;  // station index (output row)
    const unsigned b     = token >> 12;      // token / T  (T = 4096)
    const int lab = lab_idx[b];

    // ---- projection: o[f] = sum_n x[token,n,f] * proj[lab,n,m] + bias[lab,0,m,f]
    const float4* xp4 = reinterpret_cast<const float4*>(x) + (size_t)token * (NN * FF / 4);
    const float*  Wp  = proj + (size_t)lab * (NN * NN) + m;            // stride 11 over n
    const float4* bp4 = reinterpret_cast<const float4*>(bias) + (size_t)lab * (NN * FF / 4) + m * (FF / 4);

    float o[FF];
    #pragma unroll
    for (int f4 = 0; f4 < FF / 4; ++f4) {
        float4 v = bp4[f4];
        o[f4 * 4 + 0] = v.x; o[f4 * 4 + 1] = v.y;
        o[f4 * 4 + 2] = v.z; o[f4 * 4 + 3] = v.w;
    }
    #pragma unroll
    for (int n = 0; n < NN; ++n) {
        const float wnm = Wp[n * NN];
        #pragma unroll
        for (int f4 = 0; f4 < FF / 4; ++f4) {
            float4 v = xp4[n * (FF / 4) + f4];
            o[f4 * 4 + 0] = fmaf(v.x, wnm, o[f4 * 4 + 0]);
            o[f4 * 4 + 1] = fmaf(v.y, wnm, o[f4 * 4 + 1]);
            o[f4 * 4 + 2] = fmaf(v.z, wnm, o[f4 * 4 + 2]);
            o[f4 * 4 + 3] = fmaf(v.w, wnm, o[f4 * 4 + 3]);
        }
    }

    // ---- h = o @ w1 + b1   (w1 indices are unroll-constant + uniform ptr -> s_load)
    float h[HH];
    #pragma unroll
    for (int j = 0; j < HH; ++j) h[j] = b1[j];
    #pragma unroll
    for (int f = 0; f < FF; ++f) {
        const float xf = o[f];
        #pragma unroll
        for (int j = 0; j < HH; ++j) h[j] = fmaf(xf, w1[f * HH + j], h[j]);
    }

    // ---- LayerNorm over H
    float s = 0.f, ss = 0.f;
    #pragma unroll
    for (int j = 0; j < HH; ++j) { s += h[j]; ss += h[j] * h[j]; }
    const float mu   = s * (1.f / HH);
    const float var  = ss * (1.f / HH) - mu * mu;
    const float rstd = rsqrtf(var + LN_EPS);

    // ---- affine + fast GELU (tanh form)
    #pragma unroll
    for (int j = 0; j < HH; ++j) {
        float v = (h[j] - mu) * rstd * ln_g[j] + ln_b[j];
        h[j] = fast_gelu(v);
    }

    // ---- o2 = h @ w2 + b2
    float o2[FF];
    #pragma unroll
    for (int f = 0; f < FF; ++f) o2[f] = b2[f];
    #pragma unroll
    for (int j = 0; j < HH; ++j) {
        const float hj = h[j];
        #pragma unroll
        for (int f = 0; f < FF; ++f) o2[f] = fmaf(hj, w2[j * FF + f], o2[f]);
    }

    // ---- store 64 contiguous bytes at out + w*16 floats
    float4* op4 = reinterpret_cast<float4*>(out) + (size_t)w * (FF / 4);
    #pragma unroll
    for (int f4 = 0; f4 < FF / 4; ++f4) {
        op4[f4] = make_float4(o2[f4 * 4 + 0], o2[f4 * 4 + 1],
                              o2[f4 * 4 + 2], o2[f4 * 4 + 3]);
    }
}

extern "C" void kernel_launch(void* const* d_in, const int* in_sizes, int n_in,
                              void* d_out, int out_size, void* d_ws, size_t ws_size,
                              hipStream_t stream) {
    const float* x       = (const float*)d_in[0];
    const int*   lab_idx = (const int*)  d_in[1];
    const float* proj    = (const float*)d_in[2];
    const float* bias    = (const float*)d_in[3];
    const float* w1      = (const float*)d_in[4];
    const float* b1      = (const float*)d_in[5];
    const float* ln_g    = (const float*)d_in[6];
    const float* ln_b    = (const float*)d_in[7];
    const float* w2      = (const float*)d_in[8];
    const float* b2      = (const float*)d_in[9];
    float* out = (float*)d_out;

    const int blocks = (TOTAL_ITEMS + 255) / 256;  // 5632
    fused_proj_mlp_kernel<<<blocks, 256, 0, stream>>>(
        x, lab_idx, proj, bias, w1, b1, ln_g, ln_b, w2, b2, out);
}

// Round 3
// 222.941 us; speedup vs baseline: 1.1600x; 1.1600x over previous
//
#include <hip/hip_runtime.h>
#include <hip/hip_bf16.h>
#include <math.h>

#define BB 32
#define TT 4096
#define NN 11
#define FF 16
#define HH 32
#define LN_EPS 1e-5f
#define TOTAL_ROWS (BB * TT * NN)      // 1,441,792
#define ROWS_PER_BLOCK 256
#define NBLOCKS (TOTAL_ROWS / ROWS_PER_BLOCK)       // 5632
#define BLOCKS_PER_BATCH (TT * NN / ROWS_PER_BLOCK) // 176 (exact)

typedef __attribute__((ext_vector_type(8))) short short8;  // 8 bf16 = 4 VGPRs
typedef __attribute__((ext_vector_type(4))) float f32x4;

union Frag { unsigned u[4]; uint4 u4; short8 v; };

__device__ __forceinline__ unsigned pack2_bf16(float a, float b) {
    __hip_bfloat162 p = __float22bfloat162_rn(make_float2(a, b));
    union { __hip_bfloat162 h; unsigned u; } cvt; cvt.h = p; return cvt.u;
}
__device__ __forceinline__ unsigned short to_bf16u(float a) {
    __hip_bfloat16 h = __float2bfloat16(a);
    union { __hip_bfloat16 h; unsigned short u; } cvt; cvt.h = h; return cvt.u;
}

// tanh-form GELU via sigmoid; max dev from exact ~3e-3
__device__ __forceinline__ float fast_gelu(float v) {
    const float v2 = v * v;
    const float c  = fmaf(0.044715f, v2, 1.0f);
    const float t  = v * c * 1.5957691216057308f;
    const float e  = __expf(-t);
    return v * __builtin_amdgcn_rcpf(1.0f + e);
}

__global__ __launch_bounds__(256) void fused_proj_mlp_mfma(
    const float* __restrict__ x,        // [B,T,N,F]
    const int*   __restrict__ lab_idx,  // [B]
    const float* __restrict__ proj,     // [L,N,N]
    const float* __restrict__ bias,     // [L,1,N,F]
    const float* __restrict__ w1,       // [F,H]
    const float* __restrict__ b1,       // [H]
    const float* __restrict__ ln_g,     // [H]
    const float* __restrict__ ln_b,     // [H]
    const float* __restrict__ w2,       // [H,F]
    const float* __restrict__ b2,       // [F]
    float*       __restrict__ out)      // [B,T,N,F]
{
    // per-wave o staging: 64 rows x 8 bf16-pair dwords, stride 12 dwords (48 B = 3x16)
    __shared__ unsigned o_st[4][64][12];
    // per-wave per-tile h staging: 16 rows x 32 bf16, stride 40 (80 B = 5x16)
    __shared__ unsigned short h_st[4][4][16][40];

    const int tid  = threadIdx.x;
    const int wv   = tid >> 6;     // wave 0..3
    const int lane = tid & 63;
    const int q    = lane >> 4;    // quad 0..3
    const int c    = lane & 15;

    const int row      = blockIdx.x * ROWS_PER_BLOCK + tid;  // this lane's projection row
    const unsigned token = (unsigned)row / 11u;
    const int m        = row - (int)(token * 11u);
    const int bidx     = blockIdx.x / BLOCKS_PER_BATCH;      // uniform per block
    const int lab      = lab_idx[bidx];

    // ---------------- preload weight fragments (once per thread) ----------------
    // B-frag layout: lane holds B[k = 8q + j][n = c], j=0..7 (pairs lo/hi per dword)
    Frag b1a, b1b, b2f;
    #pragma unroll
    for (int d = 0; d < 4; ++d) {
        const int k0 = 8 * q + 2 * d;
        float wa0 = 0.f, wa1 = 0.f, wb0 = 0.f, wb1 = 0.f;
        if (q < 2) {  // GEMM1 K=16: zero-pad k>=16 via zero B-frags
            wa0 = w1[k0 * HH + c];        wa1 = w1[(k0 + 1) * HH + c];
            wb0 = w1[k0 * HH + 16 + c];   wb1 = w1[(k0 + 1) * HH + 16 + c];
        }
        b1a.u[d] = pack2_bf16(wa0, wa1);
        b1b.u[d] = pack2_bf16(wb0, wb1);
        b2f.u[d] = pack2_bf16(w2[k0 * FF + c], w2[(k0 + 1) * FF + c]);
    }
    const float b1c_a = b1[c], b1c_b = b1[16 + c], b2c = b2[c];

    float g8[8], e8[8];
    {
        const float4* gp = reinterpret_cast<const float4*>(ln_g + 8 * q);
        const float4* bp = reinterpret_cast<const float4*>(ln_b + 8 * q);
        float4 g0 = gp[0], g1 = gp[1], e0 = bp[0], e1 = bp[1];
        g8[0]=g0.x; g8[1]=g0.y; g8[2]=g0.z; g8[3]=g0.w;
        g8[4]=g1.x; g8[5]=g1.y; g8[6]=g1.z; g8[7]=g1.w;
        e8[0]=e0.x; e8[1]=e0.y; e8[2]=e0.z; e8[3]=e0.w;
        e8[4]=e1.x; e8[5]=e1.y; e8[6]=e1.z; e8[7]=e1.w;
    }

    // ---------------- step A: fp32 projection (exact) ----------------
    const float4* xp4 = reinterpret_cast<const float4*>(x) + (size_t)token * (NN * FF / 4);
    const float*  Wp  = proj + (size_t)lab * (NN * NN) + m;
    const float4* bp4 = reinterpret_cast<const float4*>(bias) + (size_t)lab * (NN * FF / 4) + m * (FF / 4);

    float o[FF];
    #pragma unroll
    for (int f4 = 0; f4 < FF / 4; ++f4) {
        float4 v = bp4[f4];
        o[f4*4+0] = v.x; o[f4*4+1] = v.y; o[f4*4+2] = v.z; o[f4*4+3] = v.w;
    }
    #pragma unroll
    for (int n = 0; n < NN; ++n) {
        const float wnm = Wp[n * NN];
        #pragma unroll
        for (int f4 = 0; f4 < FF / 4; ++f4) {
            float4 v = xp4[n * (FF / 4) + f4];
            o[f4*4+0] = fmaf(v.x, wnm, o[f4*4+0]);
            o[f4*4+1] = fmaf(v.y, wnm, o[f4*4+1]);
            o[f4*4+2] = fmaf(v.z, wnm, o[f4*4+2]);
            o[f4*4+3] = fmaf(v.w, wnm, o[f4*4+3]);
        }
    }

    // pack o -> bf16 pairs, stage to LDS (row = lane, 2x b128)
    {
        unsigned op[8];
        #pragma unroll
        for (int d = 0; d < 8; ++d) op[d] = pack2_bf16(o[2*d], o[2*d+1]);
        uint4* dst = reinterpret_cast<uint4*>(&o_st[wv][lane][0]);
        dst[0] = make_uint4(op[0], op[1], op[2], op[3]);
        dst[1] = make_uint4(op[4], op[5], op[6], op[7]);
    }
    __syncthreads();

    const int qo = (q & 1) * 4;  // safe o-chunk; q>=2 reads garbage but B1-frag is 0 there

    #pragma unroll
    for (int tt = 0; tt < 4; ++tt) {
        // ---- GEMM1: A-frag lane holds A[m=c][k=8q+j] (k=f; zero-padded k>=16)
        Frag a1;
        a1.u4 = *reinterpret_cast<const uint4*>(&o_st[wv][tt * 16 + c][qo]);
        f32x4 acc1a = { b1c_a, b1c_a, b1c_a, b1c_a };
        f32x4 acc1b = { b1c_b, b1c_b, b1c_b, b1c_b };
        acc1a = __builtin_amdgcn_mfma_f32_16x16x32_bf16(a1.v, b1a.v, acc1a, 0, 0, 0);
        acc1b = __builtin_amdgcn_mfma_f32_16x16x32_bf16(a1.v, b1b.v, acc1b, 0, 0, 0);

        // ---- transpose h (C-layout -> row-major bf16) through LDS
        #pragma unroll
        for (int i = 0; i < 4; ++i) {
            h_st[wv][tt][q * 4 + i][c]      = to_bf16u(acc1a[i]);
            h_st[wv][tt][q * 4 + i][16 + c] = to_bf16u(acc1b[i]);
        }
        __syncthreads();

        // ---- read back in A-layout: lane holds row c, k = 8q..8q+7
        Frag a2r;
        a2r.u4 = *reinterpret_cast<const uint4*>(&h_st[wv][tt][c][8 * q]);
        float hv[8];
        #pragma unroll
        for (int d = 0; d < 4; ++d) {
            union { unsigned u; float f; } lo, hi;
            lo.u = a2r.u[d] << 16; hi.u = a2r.u[d] & 0xffff0000u;
            hv[2*d] = lo.f; hv[2*d+1] = hi.f;
        }

        // ---- LN stats: 8 local + butterfly over the 4 lanes holding this row
        float s = 0.f, ss = 0.f;
        #pragma unroll
        for (int d = 0; d < 8; ++d) { s += hv[d]; ss = fmaf(hv[d], hv[d], ss); }
        s  += __shfl_xor(s, 16);  s  += __shfl_xor(s, 32);
        ss += __shfl_xor(ss, 16); ss += __shfl_xor(ss, 32);
        const float mu   = s * (1.f / HH);
        const float var  = ss * (1.f / HH) - mu * mu;
        const float rstd = rsqrtf(var + LN_EPS);
        const float nb   = -mu * rstd;

        // ---- affine + GELU + repack to A2-frag
        Frag a2;
        #pragma unroll
        for (int d = 0; d < 4; ++d) {
            float v0 = fmaf(fmaf(hv[2*d],   rstd, nb), g8[2*d],   e8[2*d]);
            float v1 = fmaf(fmaf(hv[2*d+1], rstd, nb), g8[2*d+1], e8[2*d+1]);
            a2.u[d] = pack2_bf16(fast_gelu(v0), fast_gelu(v1));
        }

        // ---- GEMM2 (K=32) + store in C-layout
        f32x4 acc2 = { b2c, b2c, b2c, b2c };
        acc2 = __builtin_amdgcn_mfma_f32_16x16x32_bf16(a2.v, b2f.v, acc2, 0, 0, 0);

        float* orow = out + ((size_t)(blockIdx.x * ROWS_PER_BLOCK + wv * 64 + tt * 16 + q * 4) * FF + c);
        #pragma unroll
        for (int i = 0; i < 4; ++i) orow[(size_t)i * FF] = acc2[i];
    }
}

extern "C" void kernel_launch(void* const* d_in, const int* in_sizes, int n_in,
                              void* d_out, int out_size, void* d_ws, size_t ws_size,
                              hipStream_t stream) {
    const float* x       = (const float*)d_in[0];
    const int*   lab_idx = (const int*)  d_in[1];
    const float* proj    = (const float*)d_in[2];
    const float* bias    = (const float*)d_in[3];
    const float* w1      = (const float*)d_in[4];
    const float* b1      = (const float*)d_in[5];
    const float* ln_g    = (const float*)d_in[6];
    const float* ln_b    = (const float*)d_in[7];
    const float* w2      = (const float*)d_in[8];
    const float* b2      = (const float*)d_in[9];
    float* out = (float*)d_out;

    fused_proj_mlp_mfma<<<NBLOCKS, 256, 0, stream>>>(
        x, lab_idx, proj, bias, w1, b1, ln_g, ln_b, w2, b2, out);
}